// Round 16
// baseline (1003.549 us; speedup 1.0000x reference)
//
#include <hip/hip_runtime.h>
#include <math.h>

#define NN      65536
#define KNN     12
#define WIDTH   256
#define GW      192
#define DEPTH   7
#define GLAYERS 4
#define FF      48

// seed grid (SAT): 192^3 cells over [-6,6]^3, cell 0.0625
#define GC    192
#define GC3   7077888
#define GLO   (-6.0f)
#define GCW   0.0625f
#define GINV  16.0f

// sort grid: 128^3 cells over [-6,6]^3, cell 0.09375 (~3.4 pts/cell at center)
#define GS     128
#define GS3    2097152
#define GSINV  10.666666667f
#define CS2    0.09375f

// lanes cooperating on one query (R14 lesson: QL=32 regressed; 16 is the sweet spot)
#define QL    16

// heavy-query threshold: r > 0.45 (~6% of queries)
#define RT2   0.2025f

// fused trunk: 128 rows/block, LDS row stride 264 f16 (528B = 16B-aligned, 2-way bank alias)
#define TSTRIDE 264

typedef __attribute__((ext_vector_type(8))) _Float16 half8;
typedef __attribute__((ext_vector_type(4))) _Float16 half4;
typedef __attribute__((ext_vector_type(4))) float    f4;

__device__ __forceinline__ float silu_f(float v) { return v / (1.0f + expf(-v)); }

// top-12 ladder on NAMED scalars
#define KSWAP(A,B,IA,IB) do { if (B < A) { float _t=A; A=B; B=_t; int _u=IA; IA=IB; IB=_u; } } while(0)
#define KINSERT(DV,IV) do { b11=(DV); j11=(IV); \
    KSWAP(b10,b11,j10,j11); KSWAP(b9,b10,j9,j10); KSWAP(b8,b9,j8,j9); \
    KSWAP(b7,b8,j7,j8);  KSWAP(b6,b7,j6,j7);  KSWAP(b5,b6,j5,j6); \
    KSWAP(b4,b5,j4,j5);  KSWAP(b3,b4,j3,j4);  KSWAP(b2,b3,j2,j3); \
    KSWAP(b1,b2,j1,j2);  KSWAP(b0,b1,j0,j1); } while(0)

__device__ __forceinline__ int cell_of(float v) {
    int c = (int)floorf((v - GLO) * GINV);
    return min(max(c, 0), GC-1);
}

__device__ __forceinline__ int cell2(float v) {
    int c = (int)floorf((v - GLO) * GSINV);
    return min(max(c, 0), GS-1);
}

// ---------------- zero both count grids (+ order counters) in one launch ----------------
__global__ __launch_bounds__(256) void zero_both_kernel(int* __restrict__ cnt,
                                                        int* __restrict__ cnt2,
                                                        int* __restrict__ octr) {
    int g = blockIdx.x*256 + threadIdx.x;
    if (g == 0) { octr[0] = 0; octr[1] = 0; octr[2] = 0; }
    if (g < GC3/4) *(int4*)&cnt[g*4] = make_int4(0,0,0,0);
    else           *(int4*)&cnt2[(g - GC3/4)*4] = make_int4(0,0,0,0);
}

// ---------------- prep (pack x+|x|^2) + both histograms in one pass ----------------
__global__ __launch_bounds__(256) void prep_hist_kernel(const float* __restrict__ x,
                                                        float4* __restrict__ xw,
                                                        int* __restrict__ cnt,
                                                        int* __restrict__ cnt2) {
    int i = blockIdx.x*256 + threadIdx.x;
    float a = x[3*i], b = x[3*i+1], c = x[3*i+2];
    xw[i] = make_float4(a, b, c, a*a + b*b + c*c);
    atomicAdd(&cnt[(cell_of(c)*GC + cell_of(b))*GC + cell_of(a)], 1);
    atomicAdd(&cnt2[(cell2(c)*GS + cell2(b))*GS + cell2(a)], 1);
}

// ---------------- SAT pass 1 (x): wave-per-row parallel prefix scan ----------------
__global__ __launch_bounds__(256) void satx_kernel(int* __restrict__ S) {
    const int wid  = (blockIdx.x*256 + threadIdx.x) >> 6;   // row index (z*GC+y)
    const int lane = threadIdx.x & 63;
    const int base = wid * GC;
    int carry = 0;
#pragma unroll
    for (int seg = 0; seg < 3; ++seg) {
        int v = S[base + seg*64 + lane];
#pragma unroll
        for (int off = 1; off < 64; off <<= 1) {
            int n = __shfl_up(v, off);
            if (lane >= off) v += n;
        }
        v += carry;
        S[base + seg*64 + lane] = v;
        carry = __shfl(v, 63);
    }
}

__global__ __launch_bounds__(256) void saty_kernel(int* __restrict__ S) {
    int t = blockIdx.x*256 + threadIdx.x;
    int z = t / GC, xx = t % GC, run = 0;
    for (int y = 0; y < GC; ++y) { int idx = (z*GC + y)*GC + xx; run += S[idx]; S[idx] = run; }
}
__global__ __launch_bounds__(256) void satz_kernel(int* __restrict__ S) {
    int t = blockIdx.x*256 + threadIdx.x;
    int y = t / GC, xx = t % GC, run = 0;
    for (int z = 0; z < GC; ++z) { int idx = (z*GC + y)*GC + xx; run += S[idx]; S[idx] = run; }
}

__device__ __forceinline__ int satv(const int* __restrict__ S, int xx, int y, int z) {
    if (xx < 0 || y < 0 || z < 0) return 0;
    return S[(z*GC + y)*GC + xx];
}

// ---------------- seed bound: exponential + binary search on R ----------------
__global__ __launch_bounds__(256) void seed_kernel(const float4* __restrict__ xw,
                                                   const int* __restrict__ S,
                                                   float* __restrict__ seed) {
    int q = blockIdx.x*256 + threadIdx.x;
    float4 me = xw[q];
    int cx = cell_of(me.x), cy = cell_of(me.y), cz = cell_of(me.z);

    auto boxcount = [&](int R) {
        int x0 = max(cx-R, 0), x1 = min(cx+R, GC-1);
        int y0 = max(cy-R, 0), y1 = min(cy+R, GC-1);
        int z0 = max(cz-R, 0), z1 = min(cz+R, GC-1);
        return satv(S,x1,y1,z1) - satv(S,x0-1,y1,z1) - satv(S,x1,y0-1,z1) - satv(S,x1,y1,z0-1)
             + satv(S,x0-1,y0-1,z1) + satv(S,x0-1,y1,z0-1) + satv(S,x1,y0-1,z0-1)
             - satv(S,x0-1,y0-1,z0-1);
    };

    int Rlo = 0, Rhi = 1;
    int c = boxcount(1);
    while (c < KNN + 1) {
        if (Rhi >= GC - 1) break;
        Rlo = Rhi;
        Rhi = min(Rhi << 1, GC - 1);
        c = boxcount(Rhi);
    }
    if (c < KNN + 1) { seed[q] = 3e38f; return; }
    while (Rlo + 1 < Rhi) {
        int Rm = (Rlo + Rhi) >> 1;
        if (boxcount(Rm) >= KNN + 1) Rhi = Rm; else Rlo = Rm;
    }
    const int R = Rhi;   // minimal R with count >= KNN+1
    int x0 = max(cx-R, 0), x1 = min(cx+R, GC-1);
    int y0 = max(cy-R, 0), y1 = min(cy+R, GC-1);
    int z0 = max(cz-R, 0), z1 = min(cz+R, GC-1);
    float dx = fmaxf(me.x - (GLO + x0*GCW), (GLO + (x1+1)*GCW) - me.x);
    float dy = fmaxf(me.y - (GLO + y0*GCW), (GLO + (y1+1)*GCW) - me.y);
    float dz = fmaxf(me.z - (GLO + z0*GCW), (GLO + (z1+1)*GCW) - me.z);
    seed[q] = (dx*dx + dy*dy + dz*dz) * 1.00002f + 1e-6f;
}

// ---------------- counting-sort scans ----------------
__global__ __launch_bounds__(256) void scan1_kernel(const int* __restrict__ cnt,
                                                    int* __restrict__ bsum) {
    __shared__ int red[256];
    const int t = threadIdx.x;
    int4 v = ((const int4*)cnt)[blockIdx.x*256 + t];
    red[t] = v.x + v.y + v.z + v.w;
    __syncthreads();
    for (int off = 128; off > 0; off >>= 1) {
        if (t < off) red[t] += red[t + off];
        __syncthreads();
    }
    if (t == 0) bsum[blockIdx.x] = red[0];
}

__global__ __launch_bounds__(256) void scan2_kernel(int* __restrict__ bsum) {
    __shared__ int red[256];
    const int t = threadIdx.x;
    int v[8]; int s = 0;
#pragma unroll
    for (int i = 0; i < 8; ++i) { v[i] = bsum[t*8 + i]; s += v[i]; }
    red[t] = s;
    __syncthreads();
    for (int off = 1; off < 256; off <<= 1) {
        int x = (t >= off) ? red[t - off] : 0;
        __syncthreads();
        red[t] += x;
        __syncthreads();
    }
    int run = red[t] - s;   // exclusive prefix of this thread's chunk
#pragma unroll
    for (int i = 0; i < 8; ++i) { int c = v[i]; bsum[t*8 + i] = run; run += c; }
}

__global__ __launch_bounds__(256) void scan3_kernel(int* __restrict__ cnt,
                                                    const int* __restrict__ bsum) {
    __shared__ int red[256];
    const int t = threadIdx.x;
    int4 v = ((const int4*)cnt)[blockIdx.x*256 + t];
    int s = v.x + v.y + v.z + v.w;
    red[t] = s;
    __syncthreads();
    for (int off = 1; off < 256; off <<= 1) {
        int x = (t >= off) ? red[t - off] : 0;
        __syncthreads();
        red[t] += x;
        __syncthreads();
    }
    int run = bsum[blockIdx.x] + red[t] - s;
    int4 o;
    o.x = run; run += v.x;
    o.y = run; run += v.y;
    o.z = run; run += v.z;
    o.w = run;
    ((int4*)cnt)[blockIdx.x*256 + t] = o;
}

// scatter into sorted order; cellStart[c] becomes inclusive end of cell c
__global__ __launch_bounds__(256) void scatter_kernel(const float4* __restrict__ xw,
                                                      int* __restrict__ cstart,
                                                      float4* __restrict__ sxw,
                                                      int* __restrict__ sid) {
    int i = blockIdx.x*256 + threadIdx.x;
    float4 p = xw[i];
    int cid = (cell2(p.z)*GS + cell2(p.y))*GS + cell2(p.x);
    int pos = atomicAdd(&cstart[cid], 1);
    sxw[pos] = p;
    sid[pos] = i;
}

// ---------------- query ordering: heavy (big seed box) first ----------------
__global__ __launch_bounds__(256) void place_kernel(const int* __restrict__ sid,
                                                    const float* __restrict__ seed,
                                                    int* __restrict__ octr,
                                                    int* __restrict__ qperm) {
    int p = blockIdx.x*256 + threadIdx.x;
    int slot;
    if (seed[sid[p]] > RT2) slot = atomicAdd(&octr[1], 1);
    else                    slot = NN - 1 - atomicAdd(&octr[2], 1);
    qperm[slot] = p;
}

// ---------------- direct exact top-12: 16 lanes/query, ROW-split + sphere prune ----------------
#define MROUND(M) do { \
    float pb0=__shfl_xor(b0,M), pb1=__shfl_xor(b1,M), pb2=__shfl_xor(b2,M), \
          pb3=__shfl_xor(b3,M), pb4=__shfl_xor(b4,M), pb5=__shfl_xor(b5,M), \
          pb6=__shfl_xor(b6,M), pb7=__shfl_xor(b7,M), pb8=__shfl_xor(b8,M), \
          pb9=__shfl_xor(b9,M), pb10=__shfl_xor(b10,M), pb11=__shfl_xor(b11,M); \
    int  pj0=__shfl_xor(j0,M), pj1=__shfl_xor(j1,M), pj2=__shfl_xor(j2,M), \
         pj3=__shfl_xor(j3,M), pj4=__shfl_xor(j4,M), pj5=__shfl_xor(j5,M), \
         pj6=__shfl_xor(j6,M), pj7=__shfl_xor(j7,M), pj8=__shfl_xor(j8,M), \
         pj9=__shfl_xor(j9,M), pj10=__shfl_xor(j10,M), pj11=__shfl_xor(j11,M); \
    if (pb0  < b11) KINSERT(pb0, pj0);   if (pb1  < b11) KINSERT(pb1, pj1); \
    if (pb2  < b11) KINSERT(pb2, pj2);   if (pb3  < b11) KINSERT(pb3, pj3); \
    if (pb4  < b11) KINSERT(pb4, pj4);   if (pb5  < b11) KINSERT(pb5, pj5); \
    if (pb6  < b11) KINSERT(pb6, pj6);   if (pb7  < b11) KINSERT(pb7, pj7); \
    if (pb8  < b11) KINSERT(pb8, pj8);   if (pb9  < b11) KINSERT(pb9, pj9); \
    if (pb10 < b11) KINSERT(pb10, pj10); if (pb11 < b11) KINSERT(pb11, pj11); \
} while(0)

__global__ __launch_bounds__(256) void knn_direct_kernel(const float4* __restrict__ sxw,
                                                         const int* __restrict__ sid,
                                                         const int* __restrict__ cend,
                                                         const float* __restrict__ seed,
                                                         const int* __restrict__ qperm,
                                                         unsigned short* __restrict__ knn_idx) {
    const int gtid = blockIdx.x*256 + threadIdx.x;
    const int p   = qperm[gtid >> 4];   // heavy-first permuted query
    const int sub = gtid & (QL-1);      // lane within query group
    const float4 me = sxw[p];
    const float qsq = me.w;
    const float rr = seed[sid[p]] + 1e-3f;   // static seed bound (>= true d12^2)
    const float r = sqrtf(rr);
    const int y0 = cell2(me.y - r), y1 = cell2(me.y + r);
    const int z0 = cell2(me.z - r), z1 = cell2(me.z + r);
    const int Wy = y1 - y0 + 1;
    const int NZ = z1 - z0 + 1;

    float b0=3e38f,b1=3e38f,b2=3e38f,b3=3e38f,b4=3e38f,b5=3e38f,
          b6=3e38f,b7=3e38f,b8=3e38f,b9=3e38f,b10=3e38f,b11=3e38f;
    int   j0=-1,j1=-1,j2=-1,j3=-1,j4=-1,j5=-1,j6=-1,j7=-1,j8=-1,j9=-1,j10=-1,j11=-1;

    // per-thread setup divisions (the ONLY divs in the kernel)
    int zi = sub / Wy;
    int yi = sub - zi*Wy;
    const int zstep = QL / Wy;
    const int ystep = QL - zstep*Wy;

    // row span with sphere pruning against per-lane dynamic bound
    auto rowspan = [&](int zi_, int yi_, int& t0, int& te) {
        t0 = 0; te = 0;
        if (zi_ < NZ) {
            int zz = z0 + zi_, yy = y0 + yi_;
            float ylo = (yy == 0)    ? -1e30f : GLO + yy*CS2;
            float yhi = (yy == GS-1) ?  1e30f : GLO + (yy+1)*CS2;
            float dy = fmaxf(0.0f, fmaxf(ylo - me.y, me.y - yhi));
            float zlo = (zz == 0)    ? -1e30f : GLO + zz*CS2;
            float zhi = (zz == GS-1) ?  1e30f : GLO + (zz+1)*CS2;
            float dz = fmaxf(0.0f, fmaxf(zlo - me.z, me.z - zhi));
            float rbl = fminf(rr, b11 * 1.00002f + 1e-6f);  // lane-dynamic bound
            float rem = rbl - dy*dy - dz*dz;
            if (rem > 0.0f) {
                float xr = sqrtf(rem);
                int xl = cell2(me.x - xr), xh = cell2(me.x + xr);
                int crow = (zz*GS + yy)*GS;
                int c0 = crow + xl;
                t0 = c0 ? cend[c0-1] : 0;
                te = cend[crow + xh];
            }
        }
    };

    int t0c, tec;
    rowspan(zi, yi, t0c, tec);
    while (zi < NZ) {
        // advance (zi,yi) by QL rows incrementally (no div)
        int ziN = zi + zstep, yiN = yi + ystep;
        if (yiN >= Wy) { yiN -= Wy; ++ziN; }
        // prefetch next owned row's span before scanning current
        int t0n, ten;
        rowspan(ziN, yiN, t0n, ten);
        for (int t = t0c; t < tec; ++t) {
            float4 c = sxw[t];
            float dot = me.x*c.x + me.y*c.y + me.z*c.z;
            float d = fmaf(-2.0f, dot, qsq + c.w);   // EXACT ref formula
            d = fmaxf(d, 0.0f);                      // ref clips at 0
            if (d < rr && d < b11 && t != p) KINSERT(d, t);  // gated; self excluded
        }
        zi = ziN; yi = yiN; t0c = t0n; tec = ten;
    }
    // merge the 16 private ladders (lanes of one group differ in bits 0..3)
    MROUND(1); MROUND(2); MROUND(4); MROUND(8);
    if (sub == 0) {
        knn_idx[p*KNN+0]=(unsigned short)j0;  knn_idx[p*KNN+1]=(unsigned short)j1;
        knn_idx[p*KNN+2]=(unsigned short)j2;  knn_idx[p*KNN+3]=(unsigned short)j3;
        knn_idx[p*KNN+4]=(unsigned short)j4;  knn_idx[p*KNN+5]=(unsigned short)j5;
        knn_idx[p*KNN+6]=(unsigned short)j6;  knn_idx[p*KNN+7]=(unsigned short)j7;
        knn_idx[p*KNN+8]=(unsigned short)j8;  knn_idx[p*KNN+9]=(unsigned short)j9;
        knn_idx[p*KNN+10]=(unsigned short)j10; knn_idx[p*KNN+11]=(unsigned short)j11;
    }
}

// ---------------- weight convert+transpose to f16 [N][K] ----------------
__global__ __launch_bounds__(256) void convert_Wt_kernel(const float* __restrict__ W,
                                                         _Float16* __restrict__ Wt) {
    int e = blockIdx.x*256 + threadIdx.x;
    int l = e >> 16, r = e & 65535;
    int n = r >> 8, k = r & 255;
    Wt[(size_t)l*65536 + n*256 + k] = (_Float16)W[(size_t)l*65536 + k*256 + n];
}

__global__ __launch_bounds__(256) void convert_Bg_kernel(const float* __restrict__ Ws,
                                                         const float* __restrict__ Wn,
                                                         _Float16* __restrict__ Bg) {
    int e = blockIdx.x*256 + threadIdx.x;
    int l = e / 73728, r = e % 73728;
    int n = r / 384, k = r % 384;
    float v = (k < 192) ? Ws[(size_t)l*36864 + k*192 + n]
                        : Wn[(size_t)l*36864 + (k-192)*192 + n];
    Bg[(size_t)l*73728 + (size_t)n*384 + k] = (_Float16)v;
}

__global__ __launch_bounds__(256) void convert_Wgo_kernel(const float* __restrict__ Wg_out,
                                                          _Float16* __restrict__ Wgo) {
    int e = blockIdx.x*256 + threadIdx.x;
    int n = e / 192, k = e % 192;
    Wgo[e] = (_Float16)Wg_out[k*256 + n];
}

// input-layer weights -> f16 [out][64] (cols 48..63 zero)
__global__ __launch_bounds__(256) void convert_Win_kernel(const float* __restrict__ W_in,
                                                          const float* __restrict__ Wg_in,
                                                          _Float16* __restrict__ WinT,
                                                          _Float16* __restrict__ WginT) {
    int e = blockIdx.x*256 + threadIdx.x;   // 16384 + 12288 = 28672 jobs
    if (e < 16384) {
        int n = e >> 6, k = e & 63;
        WinT[e] = (_Float16)(k < FF ? W_in[k*WIDTH + n] : 0.0f);
    } else {
        int e2 = e - 16384;
        int n = e2 >> 6, k = e2 & 63;
        WginT[e2] = (_Float16)(k < FF ? Wg_in[k*GW + n] : 0.0f);
    }
}

// ---------------- fourier features (SORTED order) -> f16 [N][64] ----------------
__global__ __launch_bounds__(256) void ff_kernel(const float4* __restrict__ sxw,
                                                 const float* __restrict__ Bf,
                                                 _Float16* __restrict__ fft) {
    const int n = blockIdx.x * 256 + threadIdx.x;
    const float4 pos = sxw[n];
    const float x0 = pos.x, x1 = pos.y, x2 = pos.z;
    _Float16 v[64];
#pragma unroll
    for (int sm = 0; sm < 24; ++sm) {
        int s = sm >> 3, m = sm & 7;
        float p = x0*Bf[s*24 + m] + x1*Bf[s*24 + 8 + m] + x2*Bf[s*24 + 16 + m];
        float sv, cv; sincosf(p, &sv, &cv);
        v[sm] = (_Float16)sv; v[24 + sm] = (_Float16)cv;
    }
#pragma unroll
    for (int k = 48; k < 64; ++k) v[k] = (_Float16)0.0f;
#pragma unroll
    for (int k8 = 0; k8 < 8; ++k8)
        *(half8*)&fft[(size_t)n*64 + k8*8] = *(half8*)&v[k8*8];
}

// ---------------- gather + mean over 12 neighbors (f16, half8-vectorized) ----------------
__global__ __launch_bounds__(192) void gather_mean_kernel(const _Float16* __restrict__ g,
                                                          const unsigned short* __restrict__ idx,
                                                          _Float16* __restrict__ agg) {
    __shared__ unsigned short nb[8][KNN];
    const int t = threadIdx.x;
    const int nb8 = blockIdx.x * 8;
    if (t < 96) { int nn = t / 12, kk = t - nn*12; nb[nn][kk] = idx[(nb8+nn)*KNN + kk]; }
    __syncthreads();
    const int nloc = t / 24, c8 = t % 24;
    float acc[8] = {0,0,0,0,0,0,0,0};
#pragma unroll
    for (int k = 0; k < KNN; ++k) {
        half8 v = *(const half8*)&g[(size_t)nb[nloc][k]*GW + c8*8];
#pragma unroll
        for (int u = 0; u < 8; ++u) acc[u] += (float)v[u];
    }
    half8 o;
#pragma unroll
    for (int u = 0; u < 8; ++u) o[u] = (_Float16)(acc[u] * (1.0f/12.0f));
    *(half8*)&agg[(size_t)(nb8 + nloc)*GW + c8*8] = o;
}

// ---------------- FiLM params ----------------
__global__ __launch_bounds__(256) void film_kernel(const float* __restrict__ cond,
                                                   const float* __restrict__ Wf_g,
                                                   const float* __restrict__ bf_g,
                                                   const float* __restrict__ Wf_b,
                                                   const float* __restrict__ bf_b,
                                                   float* __restrict__ film) {
    const int l = blockIdx.x, j = threadIdx.x;
    float g = bf_g[l*WIDTH + j], b = bf_b[l*WIDTH + j];
    for (int c = 0; c < 64; ++c) {
        float cv = cond[c];
        g = fmaf(cv, Wf_g[(size_t)(l*64 + c)*WIDTH + j], g);
        b = fmaf(cv, Wf_b[(size_t)(l*64 + c)*WIDTH + j], b);
    }
    film[l*2*WIDTH + j]         = 1.0f + g;
    film[l*2*WIDTH + WIDTH + j] = b;
}

// ---------------- f16 MFMA GEMM: BM=128, BN=64, 4 waves (graph/input layers) ----------------
template<int EPI>
__global__ __launch_bounds__(256) void gemm_mfma(
    const _Float16* __restrict__ A1, const _Float16* __restrict__ A2,
    const _Float16* __restrict__ Bt, int K1, int Ktot, int NC,
    const float* __restrict__ bias, const float* __restrict__ film,
    const _Float16* __restrict__ h0, _Float16* __restrict__ C, int addSkip) {
    __shared__ _Float16 As[128*40];
    __shared__ _Float16 Bs[64*40];
    const int tid = threadIdx.x;
    const int bm = blockIdx.x * 128, bn = blockIdx.y * 64;
    const int wid = tid >> 6, lane = tid & 63;
    const int wm = (wid & 1) * 64, wn = (wid >> 1) * 32;
    const int m16 = lane & 15, kq = lane >> 4;
    const int ar = tid >> 1, ah = tid & 1;
    const int br = tid >> 2, bq = tid & 3;
    f4 acc[4][2];
#pragma unroll
    for (int i = 0; i < 4; ++i)
#pragma unroll
        for (int j = 0; j < 2; ++j) acc[i][j] = (f4){0.f, 0.f, 0.f, 0.f};

    for (int kc = 0; kc < Ktot; kc += 32) {
        const _Float16* Asrc; int kl, ldA;
        if (kc < K1) { Asrc = A1; kl = kc;      ldA = K1; }
        else         { Asrc = A2; kl = kc - K1; ldA = Ktot - K1; }
        {
            const float4* src = (const float4*)&Asrc[(size_t)(bm + ar)*ldA + kl + ah*16];
            *(float4*)&As[ar*40 + ah*16]     = src[0];
            *(float4*)&As[ar*40 + ah*16 + 8] = src[1];
        }
        *(float4*)&Bs[br*40 + bq*8] = *(const float4*)&Bt[(size_t)(bn + br)*Ktot + kc + bq*8];
        __syncthreads();
        half8 af[4], bf[2];
#pragma unroll
        for (int mt = 0; mt < 4; ++mt) af[mt] = *(half8*)&As[(wm + mt*16 + m16)*40 + kq*8];
#pragma unroll
        for (int nt = 0; nt < 2; ++nt) bf[nt] = *(half8*)&Bs[(wn + nt*16 + m16)*40 + kq*8];
#pragma unroll
        for (int mt = 0; mt < 4; ++mt)
#pragma unroll
            for (int nt = 0; nt < 2; ++nt)
                acc[mt][nt] = __builtin_amdgcn_mfma_f32_16x16x32_f16(af[mt], bf[nt], acc[mt][nt], 0, 0, 0);
        __syncthreads();
    }

#pragma unroll
    for (int mt = 0; mt < 4; ++mt) {
#pragma unroll
        for (int nt = 0; nt < 2; ++nt) {
            int col = bn + wn + nt*16 + m16;
#pragma unroll
            for (int r = 0; r < 4; ++r) {
                int row = bm + wm + mt*16 + kq*4 + r;
                float v = acc[mt][nt][r];
                if (EPI == 0) {
                    v = silu_f(v + bias[col]);
                } else if (EPI == 1) {
                    v = fmaf(v + bias[col], film[col], film[NC + col]);
                    v = silu_f(v);
                    if (addSkip) v += (float)h0[(size_t)row*NC + col];
                } else {
                    v += (float)h0[(size_t)row*NC + col];
                }
                C[(size_t)row*NC + col] = (_Float16)v;
            }
        }
    }
}

// ---------------- FUSED trunk: 7 FiLM layers, activations LDS-resident ----------------
// Block = 128 rows, 4 waves, wave owns 32 rows in a PRIVATE LDS slice
// [32][TSTRIDE]. Per layer: A-frags -> regs once (same layout as gemm_mfma),
// then 4x64-col chunks {stage W, MFMA, FiLM+SiLU(+skip) epilogue -> act}.
// Epilogue overwrite of act is safe: A-frags already in regs; DS ops are
// in-order per wave; act slices are never shared across waves. Same kc
// accumulation order + per-layer f16 cast as the unfused path -> numerics
// identical. Saves 6x(33.5MB write + read) activation round-trips + 6 launches.
__global__ __launch_bounds__(256) void trunk_fused_kernel(
    const _Float16* __restrict__ hA, const _Float16* __restrict__ Wt,
    const float* __restrict__ bmlp, const float* __restrict__ film,
    const _Float16* __restrict__ h0, _Float16* __restrict__ hOut) {
    __shared__ _Float16 act[4*32*TSTRIDE];   // 66 KB: per-wave 32x256 activation slices
    __shared__ _Float16 Bs[64*TSTRIDE];      // 33 KB: 64 n-rows x 256 k weight chunk
    const int tid = threadIdx.x;
    const int wv = tid >> 6, lane = tid & 63;
    const int m16 = lane & 15, kq = lane >> 4;
    const int wsl = wv * 32 * TSTRIDE;
    const int brow = blockIdx.x * 128 + wv * 32;

    // layer-0 A-frags straight from global (hA is L2/L3-hot)
    half8 af[2][8];
#pragma unroll
    for (int mt = 0; mt < 2; ++mt)
#pragma unroll
        for (int kc = 0; kc < 8; ++kc)
            af[mt][kc] = *(const half8*)&hA[(size_t)(brow + mt*16 + m16)*WIDTH + kc*32 + kq*8];

    for (int l = 0; l < DEPTH; ++l) {
        const _Float16* Wl = Wt + (size_t)l*65536;
        const float* fg = film + l*2*WIDTH;
        const float* bb = bmlp + l*WIDTH;
        const int skip = (l == 2 || l == 5);
#pragma unroll
        for (int nc = 0; nc < 4; ++nc) {
            __syncthreads();   // prior chunk's Bs reads complete
            // stage W rows [nc*64, nc*64+64) x k 0..255 (coalesced float4)
#pragma unroll
            for (int j = 0; j < 8; ++j) {
                int jj = tid + j*256;
                int row = jj >> 5, k8 = jj & 31;
                *(float4*)&Bs[row*TSTRIDE + k8*8] =
                    *(const float4*)&Wl[(size_t)(nc*64 + row)*WIDTH + k8*8];
            }
            __syncthreads();
            f4 acc[2][4];
#pragma unroll
            for (int mt = 0; mt < 2; ++mt)
#pragma unroll
                for (int nt = 0; nt < 4; ++nt) acc[mt][nt] = (f4){0.f,0.f,0.f,0.f};
#pragma unroll
            for (int kc = 0; kc < 8; ++kc) {
                half8 bf[4];
#pragma unroll
                for (int nt = 0; nt < 4; ++nt)
                    bf[nt] = *(half8*)&Bs[(nt*16 + m16)*TSTRIDE + kc*32 + kq*8];
#pragma unroll
                for (int mt = 0; mt < 2; ++mt)
#pragma unroll
                    for (int nt = 0; nt < 4; ++nt)
                        acc[mt][nt] = __builtin_amdgcn_mfma_f32_16x16x32_f16(
                            af[mt][kc], bf[nt], acc[mt][nt], 0, 0, 0);
            }
            // epilogue: FiLM + SiLU (+h0 skip), write layer-(l+1) input into act
#pragma unroll
            for (int mt = 0; mt < 2; ++mt)
#pragma unroll
                for (int nt = 0; nt < 4; ++nt) {
                    int col = nc*64 + nt*16 + m16;
                    float ga = fg[col], be = fg[WIDTH + col], bi = bb[col];
#pragma unroll
                    for (int r = 0; r < 4; ++r) {
                        int lrow = mt*16 + kq*4 + r;
                        float v = fmaf(acc[mt][nt][r] + bi, ga, be);
                        v = silu_f(v);
                        if (skip) v += (float)h0[(size_t)(brow + lrow)*WIDTH + col];
                        act[wsl + lrow*TSTRIDE + col] = (_Float16)v;
                    }
                }
        }
        // next layer's A-frags from the freshly written act slice (in-wave order)
        if (l < DEPTH-1) {
#pragma unroll
            for (int mt = 0; mt < 2; ++mt)
#pragma unroll
                for (int kc = 0; kc < 8; ++kc)
                    af[mt][kc] = *(half8*)&act[wsl + (mt*16 + m16)*TSTRIDE + kc*32 + kq*8];
        }
    }
    // final activations -> global (coalesced float4)
#pragma unroll
    for (int j = 0; j < 16; ++j) {
        int jj = lane + j*64;
        int row = jj >> 5, k8 = jj & 31;
        *(float4*)&hOut[(size_t)(brow + row)*WIDTH + k8*8] =
            *(float4*)&act[wsl + row*TSTRIDE + k8*8];
    }
}

// ---------------- output head: scatter back to original order ----------------
__global__ __launch_bounds__(256) void out_kernel(const _Float16* __restrict__ h,
                                                  const int* __restrict__ sid,
                                                  const float* __restrict__ W_out,
                                                  const float* __restrict__ b_out,
                                                  float* __restrict__ out) {
    const int n = blockIdx.x * 256 + threadIdx.x;
    float a0 = 0.f, a1 = 0.f, a2 = 0.f;
#pragma unroll 4
    for (int k8 = 0; k8 < WIDTH/8; ++k8) {
        half8 v = *(const half8*)&h[(size_t)n*WIDTH + k8*8];
#pragma unroll
        for (int u = 0; u < 8; ++u) {
            float f = (float)v[u]; int k = k8*8 + u;
            a0 = fmaf(f, W_out[k*3+0], a0);
            a1 = fmaf(f, W_out[k*3+1], a1);
            a2 = fmaf(f, W_out[k*3+2], a2);
        }
    }
    const int o = sid[n];
    out[o*3+0] = (a0 + b_out[0]) * 0.01f;
    out[o*3+1] = (a1 + b_out[1]) * 0.01f;
    out[o*3+2] = (a2 + b_out[2]) * 0.01f;
}

extern "C" void kernel_launch(void* const* d_in, const int* in_sizes, int n_in,
                              void* d_out, int out_size, void* d_ws, size_t ws_size,
                              hipStream_t stream) {
    const float* x      = (const float*)d_in[0];
    const float* cond   = (const float*)d_in[1];
    const float* Bf     = (const float*)d_in[2];
    const float* W_in   = (const float*)d_in[3];
    const float* b_in   = (const float*)d_in[4];
    const float* Wg_in  = (const float*)d_in[5];
    const float* bg_in  = (const float*)d_in[6];
    const float* Ws     = (const float*)d_in[7];
    const float* Wn     = (const float*)d_in[8];
    const float* bg     = (const float*)d_in[9];
    const float* Wg_out = (const float*)d_in[10];
    const float* W      = (const float*)d_in[11];
    const float* bmlp   = (const float*)d_in[12];
    const float* Wf_g   = (const float*)d_in[13];
    const float* bf_g   = (const float*)d_in[14];
    const float* Wf_b   = (const float*)d_in[15];
    const float* bf_b   = (const float*)d_in[16];
    const float* W_out  = (const float*)d_in[17];
    const float* b_out  = (const float*)d_in[18];
    float* out = (float*)d_out;

    char* ws = (char*)d_ws;
    // slot 0 (persistent, never overlaid):
    unsigned short* knn_idx = (unsigned short*)(ws + 0);   // 1,572,864 (u16 sorted positions)
    int*       sid     = (int*)      (ws + 1572864);    //    262,144 (persist to out_kernel)
    int*       qperm   = (int*)      (ws + 1835008);    //    262,144 (heavy-first query order)
    int*       octr    = (int*)      (ws + 2097152);    //         12 (order counters)
    float4*    xw      = (float4*)   (ws + 3145728);    //  1,048,576
    // input-layer weight transposes overlay xw (xw dead after scatter_kernel)
    _Float16*  WinT    = (_Float16*) (ws + 3145728);    //     32,768
    _Float16*  WginT   = (_Float16*) (ws + 3178496);    //     24,576
    float*     film    = (float*)    (ws + 4194304);    //     14,336
    _Float16*  Bg_t    = (_Float16*) (ws + 4210688);    //    589,824
    _Float16*  Wgo_t   = (_Float16*) (ws + 4800512);    //     98,304
    _Float16*  Wt      = (_Float16*) (ws + 4898816);    //    917,504
    _Float16*  h0      = (_Float16*) (ws + 5816320);    // 33,554,432 (f16)
    // SAT + seed overlay h0 region (both dead before the h0-gemm writes h0)
    int*       cnt     = (int*)      (ws + 5816320);    // 28,311,552 (192^3 SAT in place)
    float*     seed    = (float*)    (ws + 34127872);   //    262,144
    _Float16*  g_a     = (_Float16*) (ws + 39370752);   // 25,165,824
    // sort-grid arrays overlay g_a (all dead before the g0-gemm writes g_a):
    int*       cellCnt = (int*)      (ws + 39370752);   //  8,388,608 (128^3)
    int*       bsum    = (int*)      (ws + 47759360);   //      8,192
    float4*    sxw     = (float4*)   (ws + 47767552);   //  1,048,576 (read by ff before g_a gemm)
    _Float16*  g_b     = (_Float16*) (ws + 64536576);   // 25,165,824
    _Float16*  agg     = (_Float16*) (ws + 89702400);   // 25,165,824
    _Float16*  hA      = (_Float16*) (ws + 114868224);  // 33,554,432
    _Float16*  hB      = (_Float16*) (ws + 148422656);  // 33,554,432 -> ends 181,977,088
    // fourier features overlay hB (dead until trunk writes hB)
    _Float16*  fft     = (_Float16*) (ws + 148422656);  //  8,388,608

    // --- kNN: SAT seed bound -> counting sort into 128^3 cells -> direct exact top-12 ---
    zero_both_kernel<<<(GC3+GS3)/1024, 256, 0, stream>>>(cnt, cellCnt, octr);
    prep_hist_kernel<<<NN/256, 256, 0, stream>>>(x, xw, cnt, cellCnt);
    satx_kernel<<<GC*GC/4, 256, 0, stream>>>(cnt);   // wave-per-row: 36864 waves
    saty_kernel<<<GC*GC/256, 256, 0, stream>>>(cnt);
    satz_kernel<<<GC*GC/256, 256, 0, stream>>>(cnt);
    seed_kernel<<<NN/256, 256, 0, stream>>>(xw, cnt, seed);

    scan1_kernel<<<GS3/1024, 256, 0, stream>>>(cellCnt, bsum);
    scan2_kernel<<<1, 256, 0, stream>>>(bsum);
    scan3_kernel<<<GS3/1024, 256, 0, stream>>>(cellCnt, bsum);
    scatter_kernel<<<NN/256, 256, 0, stream>>>(xw, cellCnt, sxw, sid);
    place_kernel<<<NN/256, 256, 0, stream>>>(sid, seed, octr, qperm);
    knn_direct_kernel<<<NN*QL/256, 256, 0, stream>>>(sxw, sid, cellCnt, seed, qperm, knn_idx);

    // --- network (all per-node arrays in SORTED order) ---
    film_kernel<<<DEPTH, 256, 0, stream>>>(cond, Wf_g, bf_g, Wf_b, bf_b, film);
    convert_Wt_kernel<<<DEPTH*65536/256, 256, 0, stream>>>(W, Wt);
    convert_Bg_kernel<<<GLAYERS*73728/256, 256, 0, stream>>>(Ws, Wn, Bg_t);
    convert_Wgo_kernel<<<256*192/256, 256, 0, stream>>>(Wg_out, Wgo_t);
    convert_Win_kernel<<<28672/256, 256, 0, stream>>>(W_in, Wg_in, WinT, WginT);
    ff_kernel<<<NN/256, 256, 0, stream>>>(sxw, Bf, fft);
    // h0 = silu(ff @ W_in + b_in); g_a = silu(ff @ Wg_in + bg_in)  [MFMA, K=64]
    gemm_mfma<0><<<dim3(NN/128, WIDTH/64), 256, 0, stream>>>(
        fft, nullptr, WinT, 64, 64, WIDTH, b_in, nullptr, nullptr, h0, 0);
    gemm_mfma<0><<<dim3(NN/128, GW/64), 256, 0, stream>>>(
        fft, nullptr, WginT, 64, 64, GW, bg_in, nullptr, nullptr, g_a, 0);

    _Float16* gin = g_a; _Float16* gout = g_b;
    for (int l = 0; l < GLAYERS; ++l) {
        gather_mean_kernel<<<NN/8, 192, 0, stream>>>(gin, knn_idx, agg);
        gemm_mfma<0><<<dim3(NN/128, GW/64), 256, 0, stream>>>(
            gin, agg, Bg_t + (size_t)l*73728, GW, 2*GW, GW,
            bg + l*GW, nullptr, nullptr, gout, 0);
        _Float16* t = gin; gin = gout; gout = t;
    }
    // gin == g_a (4 swaps). inject: hA = h0 + gin @ Wg_out
    gemm_mfma<2><<<dim3(NN/128, WIDTH/64), 256, 0, stream>>>(
        gin, nullptr, Wgo_t, GW, GW, WIDTH, nullptr, nullptr, h0, hA, 0);

    // fused trunk: hB = FiLM-MLP^7(hA)
    trunk_fused_kernel<<<NN/128, 256, 0, stream>>>(hA, Wt, bmlp, film, h0, hB);

    out_kernel<<<NN/256, 256, 0, stream>>>(hB, sid, W_out, b_out, out);
}

// Round 17
// 909.148 us; speedup vs baseline: 1.1038x; 1.1038x over previous
//
#include <hip/hip_runtime.h>
#include <math.h>

#define NN      65536
#define KNN     12
#define WIDTH   256
#define GW      192
#define DEPTH   7
#define GLAYERS 4
#define FF      48

// seed grid (SAT): 192^3 cells over [-6,6]^3, cell 0.0625
#define GC    192
#define GC3   7077888
#define GLO   (-6.0f)
#define GCW   0.0625f
#define GINV  16.0f

// sort grid: 128^3 cells over [-6,6]^3, cell 0.09375 (~3.4 pts/cell at center)
#define GS     128
#define GS3    2097152
#define GSINV  10.666666667f
#define CS2    0.09375f

// lanes cooperating on one query (R14 lesson: QL=32 regressed; 16 is the sweet spot)
#define QL    16

// heavy-query threshold: r > 0.45 (~6% of queries)
#define RT2   0.2025f

typedef __attribute__((ext_vector_type(8))) _Float16 half8;
typedef __attribute__((ext_vector_type(4))) _Float16 half4;
typedef __attribute__((ext_vector_type(4))) float    f4;

__device__ __forceinline__ float silu_f(float v) { return v / (1.0f + expf(-v)); }

// top-12 ladder on NAMED scalars
#define KSWAP(A,B,IA,IB) do { if (B < A) { float _t=A; A=B; B=_t; int _u=IA; IA=IB; IB=_u; } } while(0)
#define KINSERT(DV,IV) do { b11=(DV); j11=(IV); \
    KSWAP(b10,b11,j10,j11); KSWAP(b9,b10,j9,j10); KSWAP(b8,b9,j8,j9); \
    KSWAP(b7,b8,j7,j8);  KSWAP(b6,b7,j6,j7);  KSWAP(b5,b6,j5,j6); \
    KSWAP(b4,b5,j4,j5);  KSWAP(b3,b4,j3,j4);  KSWAP(b2,b3,j2,j3); \
    KSWAP(b1,b2,j1,j2);  KSWAP(b0,b1,j0,j1); } while(0)

__device__ __forceinline__ int cell_of(float v) {
    int c = (int)floorf((v - GLO) * GINV);
    return min(max(c, 0), GC-1);
}

__device__ __forceinline__ int cell2(float v) {
    int c = (int)floorf((v - GLO) * GSINV);
    return min(max(c, 0), GS-1);
}

// ---------------- zero both count grids (+ order counters) in one launch ----------------
__global__ __launch_bounds__(256) void zero_both_kernel(int* __restrict__ cnt,
                                                        int* __restrict__ cnt2,
                                                        int* __restrict__ octr) {
    int g = blockIdx.x*256 + threadIdx.x;
    if (g == 0) { octr[0] = 0; octr[1] = 0; octr[2] = 0; }
    if (g < GC3/4) *(int4*)&cnt[g*4] = make_int4(0,0,0,0);
    else           *(int4*)&cnt2[(g - GC3/4)*4] = make_int4(0,0,0,0);
}

// ---------------- prep (pack x+|x|^2) + both histograms in one pass ----------------
__global__ __launch_bounds__(256) void prep_hist_kernel(const float* __restrict__ x,
                                                        float4* __restrict__ xw,
                                                        int* __restrict__ cnt,
                                                        int* __restrict__ cnt2) {
    int i = blockIdx.x*256 + threadIdx.x;
    float a = x[3*i], b = x[3*i+1], c = x[3*i+2];
    xw[i] = make_float4(a, b, c, a*a + b*b + c*c);
    atomicAdd(&cnt[(cell_of(c)*GC + cell_of(b))*GC + cell_of(a)], 1);
    atomicAdd(&cnt2[(cell2(c)*GS + cell2(b))*GS + cell2(a)], 1);
}

// ---------------- SAT pass 1 (x): wave-per-row parallel prefix scan ----------------
__global__ __launch_bounds__(256) void satx_kernel(int* __restrict__ S) {
    const int wid  = (blockIdx.x*256 + threadIdx.x) >> 6;   // row index (z*GC+y)
    const int lane = threadIdx.x & 63;
    const int base = wid * GC;
    int carry = 0;
#pragma unroll
    for (int seg = 0; seg < 3; ++seg) {
        int v = S[base + seg*64 + lane];
#pragma unroll
        for (int off = 1; off < 64; off <<= 1) {
            int n = __shfl_up(v, off);
            if (lane >= off) v += n;
        }
        v += carry;
        S[base + seg*64 + lane] = v;
        carry = __shfl(v, 63);
    }
}

__global__ __launch_bounds__(256) void saty_kernel(int* __restrict__ S) {
    int t = blockIdx.x*256 + threadIdx.x;
    int z = t / GC, xx = t % GC, run = 0;
    for (int y = 0; y < GC; ++y) { int idx = (z*GC + y)*GC + xx; run += S[idx]; S[idx] = run; }
}
__global__ __launch_bounds__(256) void satz_kernel(int* __restrict__ S) {
    int t = blockIdx.x*256 + threadIdx.x;
    int y = t / GC, xx = t % GC, run = 0;
    for (int z = 0; z < GC; ++z) { int idx = (z*GC + y)*GC + xx; run += S[idx]; S[idx] = run; }
}

__device__ __forceinline__ int satv(const int* __restrict__ S, int xx, int y, int z) {
    if (xx < 0 || y < 0 || z < 0) return 0;
    return S[(z*GC + y)*GC + xx];
}

// ---------------- seed bound: exponential + binary search on R ----------------
__global__ __launch_bounds__(256) void seed_kernel(const float4* __restrict__ xw,
                                                   const int* __restrict__ S,
                                                   float* __restrict__ seed) {
    int q = blockIdx.x*256 + threadIdx.x;
    float4 me = xw[q];
    int cx = cell_of(me.x), cy = cell_of(me.y), cz = cell_of(me.z);

    auto boxcount = [&](int R) {
        int x0 = max(cx-R, 0), x1 = min(cx+R, GC-1);
        int y0 = max(cy-R, 0), y1 = min(cy+R, GC-1);
        int z0 = max(cz-R, 0), z1 = min(cz+R, GC-1);
        return satv(S,x1,y1,z1) - satv(S,x0-1,y1,z1) - satv(S,x1,y0-1,z1) - satv(S,x1,y1,z0-1)
             + satv(S,x0-1,y0-1,z1) + satv(S,x0-1,y1,z0-1) + satv(S,x1,y0-1,z0-1)
             - satv(S,x0-1,y0-1,z0-1);
    };

    int Rlo = 0, Rhi = 1;
    int c = boxcount(1);
    while (c < KNN + 1) {
        if (Rhi >= GC - 1) break;
        Rlo = Rhi;
        Rhi = min(Rhi << 1, GC - 1);
        c = boxcount(Rhi);
    }
    if (c < KNN + 1) { seed[q] = 3e38f; return; }
    while (Rlo + 1 < Rhi) {
        int Rm = (Rlo + Rhi) >> 1;
        if (boxcount(Rm) >= KNN + 1) Rhi = Rm; else Rlo = Rm;
    }
    const int R = Rhi;   // minimal R with count >= KNN+1
    int x0 = max(cx-R, 0), x1 = min(cx+R, GC-1);
    int y0 = max(cy-R, 0), y1 = min(cy+R, GC-1);
    int z0 = max(cz-R, 0), z1 = min(cz+R, GC-1);
    float dx = fmaxf(me.x - (GLO + x0*GCW), (GLO + (x1+1)*GCW) - me.x);
    float dy = fmaxf(me.y - (GLO + y0*GCW), (GLO + (y1+1)*GCW) - me.y);
    float dz = fmaxf(me.z - (GLO + z0*GCW), (GLO + (z1+1)*GCW) - me.z);
    seed[q] = (dx*dx + dy*dy + dz*dz) * 1.00002f + 1e-6f;
}

// ---------------- counting-sort scans ----------------
__global__ __launch_bounds__(256) void scan1_kernel(const int* __restrict__ cnt,
                                                    int* __restrict__ bsum) {
    __shared__ int red[256];
    const int t = threadIdx.x;
    int4 v = ((const int4*)cnt)[blockIdx.x*256 + t];
    red[t] = v.x + v.y + v.z + v.w;
    __syncthreads();
    for (int off = 128; off > 0; off >>= 1) {
        if (t < off) red[t] += red[t + off];
        __syncthreads();
    }
    if (t == 0) bsum[blockIdx.x] = red[0];
}

__global__ __launch_bounds__(256) void scan2_kernel(int* __restrict__ bsum) {
    __shared__ int red[256];
    const int t = threadIdx.x;
    int v[8]; int s = 0;
#pragma unroll
    for (int i = 0; i < 8; ++i) { v[i] = bsum[t*8 + i]; s += v[i]; }
    red[t] = s;
    __syncthreads();
    for (int off = 1; off < 256; off <<= 1) {
        int x = (t >= off) ? red[t - off] : 0;
        __syncthreads();
        red[t] += x;
        __syncthreads();
    }
    int run = red[t] - s;   // exclusive prefix of this thread's chunk
#pragma unroll
    for (int i = 0; i < 8; ++i) { int c = v[i]; bsum[t*8 + i] = run; run += c; }
}

__global__ __launch_bounds__(256) void scan3_kernel(int* __restrict__ cnt,
                                                    const int* __restrict__ bsum) {
    __shared__ int red[256];
    const int t = threadIdx.x;
    int4 v = ((const int4*)cnt)[blockIdx.x*256 + t];
    int s = v.x + v.y + v.z + v.w;
    red[t] = s;
    __syncthreads();
    for (int off = 1; off < 256; off <<= 1) {
        int x = (t >= off) ? red[t - off] : 0;
        __syncthreads();
        red[t] += x;
        __syncthreads();
    }
    int run = bsum[blockIdx.x] + red[t] - s;
    int4 o;
    o.x = run; run += v.x;
    o.y = run; run += v.y;
    o.z = run; run += v.z;
    o.w = run;
    ((int4*)cnt)[blockIdx.x*256 + t] = o;
}

// scatter into sorted order; cellStart[c] becomes inclusive end of cell c
__global__ __launch_bounds__(256) void scatter_kernel(const float4* __restrict__ xw,
                                                      int* __restrict__ cstart,
                                                      float4* __restrict__ sxw,
                                                      int* __restrict__ sid) {
    int i = blockIdx.x*256 + threadIdx.x;
    float4 p = xw[i];
    int cid = (cell2(p.z)*GS + cell2(p.y))*GS + cell2(p.x);
    int pos = atomicAdd(&cstart[cid], 1);
    sxw[pos] = p;
    sid[pos] = i;
}

// ---------------- query ordering: heavy (big seed box) first ----------------
__global__ __launch_bounds__(256) void place_kernel(const int* __restrict__ sid,
                                                    const float* __restrict__ seed,
                                                    int* __restrict__ octr,
                                                    int* __restrict__ qperm) {
    int p = blockIdx.x*256 + threadIdx.x;
    int slot;
    if (seed[sid[p]] > RT2) slot = atomicAdd(&octr[1], 1);
    else                    slot = NN - 1 - atomicAdd(&octr[2], 1);
    qperm[slot] = p;
}

// ---------------- direct exact top-12: 16 lanes/query, ROW-split + sphere prune ----------------
#define MROUND(M) do { \
    float pb0=__shfl_xor(b0,M), pb1=__shfl_xor(b1,M), pb2=__shfl_xor(b2,M), \
          pb3=__shfl_xor(b3,M), pb4=__shfl_xor(b4,M), pb5=__shfl_xor(b5,M), \
          pb6=__shfl_xor(b6,M), pb7=__shfl_xor(b7,M), pb8=__shfl_xor(b8,M), \
          pb9=__shfl_xor(b9,M), pb10=__shfl_xor(b10,M), pb11=__shfl_xor(b11,M); \
    int  pj0=__shfl_xor(j0,M), pj1=__shfl_xor(j1,M), pj2=__shfl_xor(j2,M), \
         pj3=__shfl_xor(j3,M), pj4=__shfl_xor(j4,M), pj5=__shfl_xor(j5,M), \
         pj6=__shfl_xor(j6,M), pj7=__shfl_xor(j7,M), pj8=__shfl_xor(j8,M), \
         pj9=__shfl_xor(j9,M), pj10=__shfl_xor(j10,M), pj11=__shfl_xor(j11,M); \
    if (pb0  < b11) KINSERT(pb0, pj0);   if (pb1  < b11) KINSERT(pb1, pj1); \
    if (pb2  < b11) KINSERT(pb2, pj2);   if (pb3  < b11) KINSERT(pb3, pj3); \
    if (pb4  < b11) KINSERT(pb4, pj4);   if (pb5  < b11) KINSERT(pb5, pj5); \
    if (pb6  < b11) KINSERT(pb6, pj6);   if (pb7  < b11) KINSERT(pb7, pj7); \
    if (pb8  < b11) KINSERT(pb8, pj8);   if (pb9  < b11) KINSERT(pb9, pj9); \
    if (pb10 < b11) KINSERT(pb10, pj10); if (pb11 < b11) KINSERT(pb11, pj11); \
} while(0)

__global__ __launch_bounds__(256) void knn_direct_kernel(const float4* __restrict__ sxw,
                                                         const int* __restrict__ sid,
                                                         const int* __restrict__ cend,
                                                         const float* __restrict__ seed,
                                                         const int* __restrict__ qperm,
                                                         unsigned short* __restrict__ knn_idx) {
    const int gtid = blockIdx.x*256 + threadIdx.x;
    const int p   = qperm[gtid >> 4];   // heavy-first permuted query
    const int sub = gtid & (QL-1);      // lane within query group
    const float4 me = sxw[p];
    const float qsq = me.w;
    const float rr = seed[sid[p]] + 1e-3f;   // static seed bound (>= true d12^2)
    const float r = sqrtf(rr);
    const int y0 = cell2(me.y - r), y1 = cell2(me.y + r);
    const int z0 = cell2(me.z - r), z1 = cell2(me.z + r);
    const int Wy = y1 - y0 + 1;
    const int NZ = z1 - z0 + 1;

    float b0=3e38f,b1=3e38f,b2=3e38f,b3=3e38f,b4=3e38f,b5=3e38f,
          b6=3e38f,b7=3e38f,b8=3e38f,b9=3e38f,b10=3e38f,b11=3e38f;
    int   j0=-1,j1=-1,j2=-1,j3=-1,j4=-1,j5=-1,j6=-1,j7=-1,j8=-1,j9=-1,j10=-1,j11=-1;

    // per-thread setup divisions (the ONLY divs in the kernel)
    int zi = sub / Wy;
    int yi = sub - zi*Wy;
    const int zstep = QL / Wy;
    const int ystep = QL - zstep*Wy;

    // row span with sphere pruning against per-lane dynamic bound
    auto rowspan = [&](int zi_, int yi_, int& t0, int& te) {
        t0 = 0; te = 0;
        if (zi_ < NZ) {
            int zz = z0 + zi_, yy = y0 + yi_;
            float ylo = (yy == 0)    ? -1e30f : GLO + yy*CS2;
            float yhi = (yy == GS-1) ?  1e30f : GLO + (yy+1)*CS2;
            float dy = fmaxf(0.0f, fmaxf(ylo - me.y, me.y - yhi));
            float zlo = (zz == 0)    ? -1e30f : GLO + zz*CS2;
            float zhi = (zz == GS-1) ?  1e30f : GLO + (zz+1)*CS2;
            float dz = fmaxf(0.0f, fmaxf(zlo - me.z, me.z - zhi));
            float rbl = fminf(rr, b11 * 1.00002f + 1e-6f);  // lane-dynamic bound
            float rem = rbl - dy*dy - dz*dz;
            if (rem > 0.0f) {
                float xr = sqrtf(rem);
                int xl = cell2(me.x - xr), xh = cell2(me.x + xr);
                int crow = (zz*GS + yy)*GS;
                int c0 = crow + xl;
                t0 = c0 ? cend[c0-1] : 0;
                te = cend[crow + xh];
            }
        }
    };

    int t0c, tec;
    rowspan(zi, yi, t0c, tec);
    while (zi < NZ) {
        // advance (zi,yi) by QL rows incrementally (no div)
        int ziN = zi + zstep, yiN = yi + ystep;
        if (yiN >= Wy) { yiN -= Wy; ++ziN; }
        // prefetch next owned row's span before scanning current
        int t0n, ten;
        rowspan(ziN, yiN, t0n, ten);
        for (int t = t0c; t < tec; ++t) {
            float4 c = sxw[t];
            float dot = me.x*c.x + me.y*c.y + me.z*c.z;
            float d = fmaf(-2.0f, dot, qsq + c.w);   // EXACT ref formula
            d = fmaxf(d, 0.0f);                      // ref clips at 0
            if (d < rr && d < b11 && t != p) KINSERT(d, t);  // gated; self excluded
        }
        zi = ziN; yi = yiN; t0c = t0n; tec = ten;
    }
    // merge the 16 private ladders (lanes of one group differ in bits 0..3)
    MROUND(1); MROUND(2); MROUND(4); MROUND(8);
    if (sub == 0) {
        knn_idx[p*KNN+0]=(unsigned short)j0;  knn_idx[p*KNN+1]=(unsigned short)j1;
        knn_idx[p*KNN+2]=(unsigned short)j2;  knn_idx[p*KNN+3]=(unsigned short)j3;
        knn_idx[p*KNN+4]=(unsigned short)j4;  knn_idx[p*KNN+5]=(unsigned short)j5;
        knn_idx[p*KNN+6]=(unsigned short)j6;  knn_idx[p*KNN+7]=(unsigned short)j7;
        knn_idx[p*KNN+8]=(unsigned short)j8;  knn_idx[p*KNN+9]=(unsigned short)j9;
        knn_idx[p*KNN+10]=(unsigned short)j10; knn_idx[p*KNN+11]=(unsigned short)j11;
    }
}

// ---------------- weight convert+transpose to f16 [N][K] ----------------
__global__ __launch_bounds__(256) void convert_Wt_kernel(const float* __restrict__ W,
                                                         _Float16* __restrict__ Wt) {
    int e = blockIdx.x*256 + threadIdx.x;
    int l = e >> 16, r = e & 65535;
    int n = r >> 8, k = r & 255;
    Wt[(size_t)l*65536 + n*256 + k] = (_Float16)W[(size_t)l*65536 + k*256 + n];
}

__global__ __launch_bounds__(256) void convert_Bg_kernel(const float* __restrict__ Ws,
                                                         const float* __restrict__ Wn,
                                                         _Float16* __restrict__ Bg) {
    int e = blockIdx.x*256 + threadIdx.x;
    int l = e / 73728, r = e % 73728;
    int n = r / 384, k = r % 384;
    float v = (k < 192) ? Ws[(size_t)l*36864 + k*192 + n]
                        : Wn[(size_t)l*36864 + (k-192)*192 + n];
    Bg[(size_t)l*73728 + (size_t)n*384 + k] = (_Float16)v;
}

__global__ __launch_bounds__(256) void convert_Wgo_kernel(const float* __restrict__ Wg_out,
                                                          _Float16* __restrict__ Wgo) {
    int e = blockIdx.x*256 + threadIdx.x;
    int n = e / 192, k = e % 192;
    Wgo[e] = (_Float16)Wg_out[k*256 + n];
}

// input-layer weights -> f16 [out][64] (cols 48..63 zero)
__global__ __launch_bounds__(256) void convert_Win_kernel(const float* __restrict__ W_in,
                                                          const float* __restrict__ Wg_in,
                                                          _Float16* __restrict__ WinT,
                                                          _Float16* __restrict__ WginT) {
    int e = blockIdx.x*256 + threadIdx.x;   // 16384 + 12288 = 28672 jobs
    if (e < 16384) {
        int n = e >> 6, k = e & 63;
        WinT[e] = (_Float16)(k < FF ? W_in[k*WIDTH + n] : 0.0f);
    } else {
        int e2 = e - 16384;
        int n = e2 >> 6, k = e2 & 63;
        WginT[e2] = (_Float16)(k < FF ? Wg_in[k*GW + n] : 0.0f);
    }
}

// ---------------- fourier features (SORTED order) -> f16 [N][64] ----------------
__global__ __launch_bounds__(256) void ff_kernel(const float4* __restrict__ sxw,
                                                 const float* __restrict__ Bf,
                                                 _Float16* __restrict__ fft) {
    const int n = blockIdx.x * 256 + threadIdx.x;
    const float4 pos = sxw[n];
    const float x0 = pos.x, x1 = pos.y, x2 = pos.z;
    _Float16 v[64];
#pragma unroll
    for (int sm = 0; sm < 24; ++sm) {
        int s = sm >> 3, m = sm & 7;
        float p = x0*Bf[s*24 + m] + x1*Bf[s*24 + 8 + m] + x2*Bf[s*24 + 16 + m];
        float sv, cv; sincosf(p, &sv, &cv);
        v[sm] = (_Float16)sv; v[24 + sm] = (_Float16)cv;
    }
#pragma unroll
    for (int k = 48; k < 64; ++k) v[k] = (_Float16)0.0f;
#pragma unroll
    for (int k8 = 0; k8 < 8; ++k8)
        *(half8*)&fft[(size_t)n*64 + k8*8] = *(half8*)&v[k8*8];
}

// ---------------- gather + mean over 12 neighbors (f16, half8-vectorized) ----------------
__global__ __launch_bounds__(192) void gather_mean_kernel(const _Float16* __restrict__ g,
                                                          const unsigned short* __restrict__ idx,
                                                          _Float16* __restrict__ agg) {
    __shared__ unsigned short nb[8][KNN];
    const int t = threadIdx.x;
    const int nb8 = blockIdx.x * 8;
    if (t < 96) { int nn = t / 12, kk = t - nn*12; nb[nn][kk] = idx[(nb8+nn)*KNN + kk]; }
    __syncthreads();
    const int nloc = t / 24, c8 = t % 24;
    float acc[8] = {0,0,0,0,0,0,0,0};
#pragma unroll
    for (int k = 0; k < KNN; ++k) {
        half8 v = *(const half8*)&g[(size_t)nb[nloc][k]*GW + c8*8];
#pragma unroll
        for (int u = 0; u < 8; ++u) acc[u] += (float)v[u];
    }
    half8 o;
#pragma unroll
    for (int u = 0; u < 8; ++u) o[u] = (_Float16)(acc[u] * (1.0f/12.0f));
    *(half8*)&agg[(size_t)(nb8 + nloc)*GW + c8*8] = o;
}

// ---------------- FiLM params ----------------
__global__ __launch_bounds__(256) void film_kernel(const float* __restrict__ cond,
                                                   const float* __restrict__ Wf_g,
                                                   const float* __restrict__ bf_g,
                                                   const float* __restrict__ Wf_b,
                                                   const float* __restrict__ bf_b,
                                                   float* __restrict__ film) {
    const int l = blockIdx.x, j = threadIdx.x;
    float g = bf_g[l*WIDTH + j], b = bf_b[l*WIDTH + j];
    for (int c = 0; c < 64; ++c) {
        float cv = cond[c];
        g = fmaf(cv, Wf_g[(size_t)(l*64 + c)*WIDTH + j], g);
        b = fmaf(cv, Wf_b[(size_t)(l*64 + c)*WIDTH + j], b);
    }
    film[l*2*WIDTH + j]         = 1.0f + g;
    film[l*2*WIDTH + WIDTH + j] = b;
}

// ---------------- f16 MFMA GEMM: BM=128, BN=64, 4 waves (R7-exact) ----------------
// R16 lesson: fusing the 7 trunk layers into one LDS-resident kernel
// REGRESSED 200->340us (101KB LDS -> 1 block/CU, 8.1M bank conflicts,
// MfmaUtil 7%); activations are L3-resident so the traffic saving was
// illusory (same lesson as R9). Separate gemms with high occupancy win.
template<int EPI>
__global__ __launch_bounds__(256) void gemm_mfma(
    const _Float16* __restrict__ A1, const _Float16* __restrict__ A2,
    const _Float16* __restrict__ Bt, int K1, int Ktot, int NC,
    const float* __restrict__ bias, const float* __restrict__ film,
    const _Float16* __restrict__ h0, _Float16* __restrict__ C, int addSkip) {
    __shared__ _Float16 As[128*40];
    __shared__ _Float16 Bs[64*40];
    const int tid = threadIdx.x;
    const int bm = blockIdx.x * 128, bn = blockIdx.y * 64;
    const int wid = tid >> 6, lane = tid & 63;
    const int wm = (wid & 1) * 64, wn = (wid >> 1) * 32;
    const int m16 = lane & 15, kq = lane >> 4;
    const int ar = tid >> 1, ah = tid & 1;
    const int br = tid >> 2, bq = tid & 3;
    f4 acc[4][2];
#pragma unroll
    for (int i = 0; i < 4; ++i)
#pragma unroll
        for (int j = 0; j < 2; ++j) acc[i][j] = (f4){0.f, 0.f, 0.f, 0.f};

    for (int kc = 0; kc < Ktot; kc += 32) {
        const _Float16* Asrc; int kl, ldA;
        if (kc < K1) { Asrc = A1; kl = kc;      ldA = K1; }
        else         { Asrc = A2; kl = kc - K1; ldA = Ktot - K1; }
        {
            const float4* src = (const float4*)&Asrc[(size_t)(bm + ar)*ldA + kl + ah*16];
            *(float4*)&As[ar*40 + ah*16]     = src[0];
            *(float4*)&As[ar*40 + ah*16 + 8] = src[1];
        }
        *(float4*)&Bs[br*40 + bq*8] = *(const float4*)&Bt[(size_t)(bn + br)*Ktot + kc + bq*8];
        __syncthreads();
        half8 af[4], bf[2];
#pragma unroll
        for (int mt = 0; mt < 4; ++mt) af[mt] = *(half8*)&As[(wm + mt*16 + m16)*40 + kq*8];
#pragma unroll
        for (int nt = 0; nt < 2; ++nt) bf[nt] = *(half8*)&Bs[(wn + nt*16 + m16)*40 + kq*8];
#pragma unroll
        for (int mt = 0; mt < 4; ++mt)
#pragma unroll
            for (int nt = 0; nt < 2; ++nt)
                acc[mt][nt] = __builtin_amdgcn_mfma_f32_16x16x32_f16(af[mt], bf[nt], acc[mt][nt], 0, 0, 0);
        __syncthreads();
    }

#pragma unroll
    for (int mt = 0; mt < 4; ++mt) {
#pragma unroll
        for (int nt = 0; nt < 2; ++nt) {
            int col = bn + wn + nt*16 + m16;
#pragma unroll
            for (int r = 0; r < 4; ++r) {
                int row = bm + wm + mt*16 + kq*4 + r;
                float v = acc[mt][nt][r];
                if (EPI == 0) {
                    v = silu_f(v + bias[col]);
                } else if (EPI == 1) {
                    v = fmaf(v + bias[col], film[col], film[NC + col]);
                    v = silu_f(v);
                    if (addSkip) v += (float)h0[(size_t)row*NC + col];
                } else {
                    v += (float)h0[(size_t)row*NC + col];
                }
                C[(size_t)row*NC + col] = (_Float16)v;
            }
        }
    }
}

// ---------------- output head: scatter back to original order ----------------
__global__ __launch_bounds__(256) void out_kernel(const _Float16* __restrict__ h,
                                                  const int* __restrict__ sid,
                                                  const float* __restrict__ W_out,
                                                  const float* __restrict__ b_out,
                                                  float* __restrict__ out) {
    const int n = blockIdx.x * 256 + threadIdx.x;
    float a0 = 0.f, a1 = 0.f, a2 = 0.f;
#pragma unroll 4
    for (int k8 = 0; k8 < WIDTH/8; ++k8) {
        half8 v = *(const half8*)&h[(size_t)n*WIDTH + k8*8];
#pragma unroll
        for (int u = 0; u < 8; ++u) {
            float f = (float)v[u]; int k = k8*8 + u;
            a0 = fmaf(f, W_out[k*3+0], a0);
            a1 = fmaf(f, W_out[k*3+1], a1);
            a2 = fmaf(f, W_out[k*3+2], a2);
        }
    }
    const int o = sid[n];
    out[o*3+0] = (a0 + b_out[0]) * 0.01f;
    out[o*3+1] = (a1 + b_out[1]) * 0.01f;
    out[o*3+2] = (a2 + b_out[2]) * 0.01f;
}

extern "C" void kernel_launch(void* const* d_in, const int* in_sizes, int n_in,
                              void* d_out, int out_size, void* d_ws, size_t ws_size,
                              hipStream_t stream) {
    const float* x      = (const float*)d_in[0];
    const float* cond   = (const float*)d_in[1];
    const float* Bf     = (const float*)d_in[2];
    const float* W_in   = (const float*)d_in[3];
    const float* b_in   = (const float*)d_in[4];
    const float* Wg_in  = (const float*)d_in[5];
    const float* bg_in  = (const float*)d_in[6];
    const float* Ws     = (const float*)d_in[7];
    const float* Wn     = (const float*)d_in[8];
    const float* bg     = (const float*)d_in[9];
    const float* Wg_out = (const float*)d_in[10];
    const float* W      = (const float*)d_in[11];
    const float* bmlp   = (const float*)d_in[12];
    const float* Wf_g   = (const float*)d_in[13];
    const float* bf_g   = (const float*)d_in[14];
    const float* Wf_b   = (const float*)d_in[15];
    const float* bf_b   = (const float*)d_in[16];
    const float* W_out  = (const float*)d_in[17];
    const float* b_out  = (const float*)d_in[18];
    float* out = (float*)d_out;

    char* ws = (char*)d_ws;
    // slot 0 (persistent, never overlaid):
    unsigned short* knn_idx = (unsigned short*)(ws + 0);   // 1,572,864 (u16 sorted positions)
    int*       sid     = (int*)      (ws + 1572864);    //    262,144 (persist to out_kernel)
    int*       qperm   = (int*)      (ws + 1835008);    //    262,144 (heavy-first query order)
    int*       octr    = (int*)      (ws + 2097152);    //         12 (order counters)
    float4*    xw      = (float4*)   (ws + 3145728);    //  1,048,576
    // input-layer weight transposes overlay xw (xw dead after scatter_kernel)
    _Float16*  WinT    = (_Float16*) (ws + 3145728);    //     32,768
    _Float16*  WginT   = (_Float16*) (ws + 3178496);    //     24,576
    float*     film    = (float*)    (ws + 4194304);    //     14,336
    _Float16*  Bg_t    = (_Float16*) (ws + 4210688);    //    589,824
    _Float16*  Wgo_t   = (_Float16*) (ws + 4800512);    //     98,304
    _Float16*  Wt      = (_Float16*) (ws + 4898816);    //    917,504
    _Float16*  h0      = (_Float16*) (ws + 5816320);    // 33,554,432 (f16)
    // SAT + seed overlay h0 region (both dead before the h0-gemm writes h0)
    int*       cnt     = (int*)      (ws + 5816320);    // 28,311,552 (192^3 SAT in place)
    float*     seed    = (float*)    (ws + 34127872);   //    262,144
    _Float16*  g_a     = (_Float16*) (ws + 39370752);   // 25,165,824
    // sort-grid arrays overlay g_a (all dead before the g0-gemm writes g_a):
    int*       cellCnt = (int*)      (ws + 39370752);   //  8,388,608 (128^3)
    int*       bsum    = (int*)      (ws + 47759360);   //      8,192
    float4*    sxw     = (float4*)   (ws + 47767552);   //  1,048,576 (read by ff before g_a gemm)
    _Float16*  g_b     = (_Float16*) (ws + 64536576);   // 25,165,824
    _Float16*  agg     = (_Float16*) (ws + 89702400);   // 25,165,824
    _Float16*  hA      = (_Float16*) (ws + 114868224);  // 33,554,432
    _Float16*  hB      = (_Float16*) (ws + 148422656);  // 33,554,432 -> ends 181,977,088
    // fourier features overlay hB (dead until trunk layer 0 writes hB)
    _Float16*  fft     = (_Float16*) (ws + 148422656);  //  8,388,608

    // --- kNN: SAT seed bound -> counting sort into 128^3 cells -> direct exact top-12 ---
    zero_both_kernel<<<(GC3+GS3)/1024, 256, 0, stream>>>(cnt, cellCnt, octr);
    prep_hist_kernel<<<NN/256, 256, 0, stream>>>(x, xw, cnt, cellCnt);
    satx_kernel<<<GC*GC/4, 256, 0, stream>>>(cnt);   // wave-per-row: 36864 waves
    saty_kernel<<<GC*GC/256, 256, 0, stream>>>(cnt);
    satz_kernel<<<GC*GC/256, 256, 0, stream>>>(cnt);
    seed_kernel<<<NN/256, 256, 0, stream>>>(xw, cnt, seed);

    scan1_kernel<<<GS3/1024, 256, 0, stream>>>(cellCnt, bsum);
    scan2_kernel<<<1, 256, 0, stream>>>(bsum);
    scan3_kernel<<<GS3/1024, 256, 0, stream>>>(cellCnt, bsum);
    scatter_kernel<<<NN/256, 256, 0, stream>>>(xw, cellCnt, sxw, sid);
    place_kernel<<<NN/256, 256, 0, stream>>>(sid, seed, octr, qperm);
    knn_direct_kernel<<<NN*QL/256, 256, 0, stream>>>(sxw, sid, cellCnt, seed, qperm, knn_idx);

    // --- network (all per-node arrays in SORTED order) ---
    film_kernel<<<DEPTH, 256, 0, stream>>>(cond, Wf_g, bf_g, Wf_b, bf_b, film);
    convert_Wt_kernel<<<DEPTH*65536/256, 256, 0, stream>>>(W, Wt);
    convert_Bg_kernel<<<GLAYERS*73728/256, 256, 0, stream>>>(Ws, Wn, Bg_t);
    convert_Wgo_kernel<<<256*192/256, 256, 0, stream>>>(Wg_out, Wgo_t);
    convert_Win_kernel<<<28672/256, 256, 0, stream>>>(W_in, Wg_in, WinT, WginT);
    ff_kernel<<<NN/256, 256, 0, stream>>>(sxw, Bf, fft);
    // h0 = silu(ff @ W_in + b_in); g_a = silu(ff @ Wg_in + bg_in)  [MFMA, K=64]
    gemm_mfma<0><<<dim3(NN/128, WIDTH/64), 256, 0, stream>>>(
        fft, nullptr, WinT, 64, 64, WIDTH, b_in, nullptr, nullptr, h0, 0);
    gemm_mfma<0><<<dim3(NN/128, GW/64), 256, 0, stream>>>(
        fft, nullptr, WginT, 64, 64, GW, bg_in, nullptr, nullptr, g_a, 0);

    _Float16* gin = g_a; _Float16* gout = g_b;
    for (int l = 0; l < GLAYERS; ++l) {
        gather_mean_kernel<<<NN/8, 192, 0, stream>>>(gin, knn_idx, agg);
        gemm_mfma<0><<<dim3(NN/128, GW/64), 256, 0, stream>>>(
            gin, agg, Bg_t + (size_t)l*73728, GW, 2*GW, GW,
            bg + l*GW, nullptr, nullptr, gout, 0);
        _Float16* t = gin; gin = gout; gout = t;
    }
    // gin == g_a (4 swaps). inject: hA = h0 + gin @ Wg_out
    gemm_mfma<2><<<dim3(NN/128, WIDTH/64), 256, 0, stream>>>(
        gin, nullptr, Wgo_t, GW, GW, WIDTH, nullptr, nullptr, h0, hA, 0);

    _Float16* hin = hA; _Float16* hout = hB;
    for (int l = 0; l < DEPTH; ++l) {
        int skip = (l == 2 || l == 5) ? 1 : 0;   // SKIPS=(3,6): after layers idx 2,5
        gemm_mfma<1><<<dim3(NN/128, WIDTH/64), 256, 0, stream>>>(
            hin, nullptr, Wt + (size_t)l*65536, WIDTH, WIDTH, WIDTH,
            bmlp + l*WIDTH, film + l*2*WIDTH, h0, hout, skip);
        _Float16* t = hin; hin = hout; hout = t;
    }
    out_kernel<<<NN/256, 256, 0, stream>>>(hin, sid, W_out, b_out, out);
}